// Round 13
// baseline (408.658 us; speedup 1.0000x reference)
//
#include <hip/hip_runtime.h>
#include <hip/hip_bf16.h>

// GCN anomaly detector: 2x GCNConv(128->128, relu) + linear(128->1).
// R13: R12's agg+GEMM fusion reverted (8x TLP loss on the latency-bound
// gather). NEW: feature-partitioned aggregation - 4 line-aligned groups of 32
// features; block b -> group (b&7)>>1 so each XCD's L2 holds only a 3.2MB
// slice of y (fits 4MB) -> gathers become L2 hits. 16 lanes x 4 edges per
// wave, one 64B line per quarter-wave. Final agg: per-group partial Wf dot,
// atomicAdd into zeroed d_out.
// Structure: fixed-capacity bucket CSR (padded bincnt); GEMM1 fused into
// scatter launch; y1 UNSCALED (agg1 applies dinv[s]); split-precision MFMA.

#define FDIM 128
#define BSHIFT 8
#define BNODES 256
#define MAXB 256
#define BPAD 16     // bincnt stride in ints (64B line per counter)
#define CHUNK 2048
#define CAP 5120    // per-bucket capacity (mean 4096, sigma 64 -> 16 sigma)

typedef unsigned int uint;
typedef unsigned short ushort;
typedef __attribute__((ext_vector_type(8))) short short8v;
typedef __attribute__((ext_vector_type(4))) float f32x4;

__device__ inline float2 bf2f(uint u) {
    return make_float2(__uint_as_float(u << 16), __uint_as_float(u & 0xffff0000u));
}
__device__ inline ushort f2bf(float f) {
    uint u = __float_as_uint(f);
    return (ushort)((u + 0x7fffu + ((u >> 16) & 1u)) >> 16);  // RNE
}
__device__ inline float bfval(ushort h) { return __uint_as_float((uint)h << 16); }
__device__ inline uint packbf2(float a, float b) {
    return (uint)f2bf(a) | ((uint)f2bf(b) << 16);
}
// XOR-swizzle 16B granules within a row by row&7 (bank spread, b128-aligned).
__device__ inline int swz(int row, int colShorts) {
    return (((colShorts >> 3) ^ (row & 7)) << 3) | (colShorts & 7);
}

// ------- MFMA GEMM core (256 thr): Y[r,:] = bf16((X@W)[r,:]*(SCALE?dinv:1)) -------
template <int CHAINS, bool SCALE>
__device__ __forceinline__ void gemm_core(int bid, const void* __restrict__ Xv,
                                          const float* __restrict__ W,
                                          const float* __restrict__ dinv,
                                          ushort* __restrict__ Y, int M,
                                          ushort (*Xh)[64], ushort (*Xl)[64],
                                          ushort (*Wth)[64], ushort (*Wtl)[64]) {
    const int t = threadIdx.x;
    const int wv = t >> 6;
    const int lane = t & 63;
    const int rb = bid * 64;

    f32x4 acc[8];
    #pragma unroll
    for (int i = 0; i < 8; ++i) acc[i] = (f32x4){0.f, 0.f, 0.f, 0.f};

    for (int kc = 0; kc < 2; ++kc) {
        const int k0 = kc * 64;
        if constexpr (CHAINS == 3) {
            const float* Xf = (const float*)Xv;
            #pragma unroll
            for (int it = 0; it < 4; ++it) {
                int idx = t + it * 256;
                int r = idx >> 4, c4 = (idx & 15) * 4;
                int gr = rb + r;
                float4 v = make_float4(0.f, 0.f, 0.f, 0.f);
                if (gr < M) v = *(const float4*)&Xf[(size_t)gr * FDIM + k0 + c4];
                ushort h0 = f2bf(v.x), h1 = f2bf(v.y), h2 = f2bf(v.z), h3 = f2bf(v.w);
                uint2 hw, lw;
                hw.x = (uint)h0 | ((uint)h1 << 16);
                hw.y = (uint)h2 | ((uint)h3 << 16);
                lw.x = (uint)f2bf(v.x - bfval(h0)) | ((uint)f2bf(v.y - bfval(h1)) << 16);
                lw.y = (uint)f2bf(v.z - bfval(h2)) | ((uint)f2bf(v.w - bfval(h3)) << 16);
                int cs = swz(r, c4);
                *(uint2*)&Xh[r][cs] = hw;
                *(uint2*)&Xl[r][cs] = lw;
            }
        } else {
            const ushort* Xb = (const ushort*)Xv;
            #pragma unroll
            for (int it = 0; it < 4; ++it) {
                int idx = t + it * 256;
                int r = idx >> 4, c4 = (idx & 15) * 4;
                int gr = rb + r;
                uint2 u = make_uint2(0u, 0u);
                if (gr < M) u = *(const uint2*)&Xb[(size_t)gr * FDIM + k0 + c4];
                *(uint2*)&Xh[r][swz(r, c4)] = u;
            }
        }
        {   // stage W chunk transposed+split (64 k x 128 n), 256 threads
            int n = t & 127, kk0 = (t >> 7) * 32;
            #pragma unroll
            for (int g = 0; g < 4; ++g) {
                uint hw[4], lw[4];
                #pragma unroll
                for (int jp = 0; jp < 4; ++jp) {
                    int k = k0 + kk0 + g * 8 + jp * 2;
                    float w0 = W[(size_t)k * FDIM + n];
                    float w1 = W[(size_t)(k + 1) * FDIM + n];
                    ushort h0 = f2bf(w0), h1 = f2bf(w1);
                    hw[jp] = (uint)h0 | ((uint)h1 << 16);
                    lw[jp] = (uint)f2bf(w0 - bfval(h0)) | ((uint)f2bf(w1 - bfval(h1)) << 16);
                }
                int cs = swz(n, kk0 + g * 8);
                *(uint4*)&Wth[n][cs] = make_uint4(hw[0], hw[1], hw[2], hw[3]);
                *(uint4*)&Wtl[n][cs] = make_uint4(lw[0], lw[1], lw[2], lw[3]);
            }
        }
        __syncthreads();
        const int arow = 16 * wv + (lane & 15);
        #pragma unroll
        for (int ks = 0; ks < 2; ++ks) {
            const int kf = ks * 32 + ((lane >> 4) << 3);
            short8v ah = *(const short8v*)&Xh[arow][swz(arow, kf)];
            short8v al;
            if constexpr (CHAINS == 3) al = *(const short8v*)&Xl[arow][swz(arow, kf)];
            #pragma unroll
            for (int ct = 0; ct < 8; ++ct) {
                int brow = 16 * ct + (lane & 15);
                int bcs = swz(brow, kf);
                short8v bh = *(const short8v*)&Wth[brow][bcs];
                short8v bl = *(const short8v*)&Wtl[brow][bcs];
                acc[ct] = __builtin_amdgcn_mfma_f32_16x16x32_bf16(ah, bh, acc[ct], 0, 0, 0);
                acc[ct] = __builtin_amdgcn_mfma_f32_16x16x32_bf16(ah, bl, acc[ct], 0, 0, 0);
                if constexpr (CHAINS == 3)
                    acc[ct] = __builtin_amdgcn_mfma_f32_16x16x32_bf16(al, bh, acc[ct], 0, 0, 0);
            }
        }
        __syncthreads();
    }
    const int rbase = rb + 16 * wv + ((lane >> 4) << 2);
    const int cbase = lane & 15;
    #pragma unroll
    for (int ri = 0; ri < 4; ++ri) {
        int R = rbase + ri;
        if (R < M) {
            float s = SCALE ? dinv[R] : 1.0f;
            ushort* Yrow = Y + (size_t)R * FDIM;
            #pragma unroll
            for (int ct = 0; ct < 8; ++ct)
                Yrow[16 * ct + cbase] = f2bf(acc[ct][ri] * s);
        }
    }
}

// ---- fused: blocks [0,nwg) bucket-scatter; blocks [nwg,..) GEMM1 (unscaled) ----
__global__ __launch_bounds__(256) void k_scat_gemm(const int* __restrict__ src,
                                                   const int* __restrict__ dst,
                                                   int* __restrict__ bincnt,
                                                   uint* __restrict__ binbuf, int E, int nwg,
                                                   const void* __restrict__ Xv,
                                                   const float* __restrict__ W,
                                                   ushort* __restrict__ Y, int M) {
    __shared__ alignas(16) ushort Xh[64][64];
    __shared__ alignas(16) ushort Xl[64][64];
    __shared__ alignas(16) ushort Wth[128][64];
    __shared__ alignas(16) ushort Wtl[128][64];
    __shared__ int h[MAXB], base[MAXB], cnt[MAXB];

    if (blockIdx.x >= nwg) {
        gemm_core<3, false>(blockIdx.x - nwg, Xv, W, nullptr, Y, M, Xh, Xl, Wth, Wtl);
        return;
    }
    int t = threadIdx.x;
    h[t] = 0;
    cnt[t] = 0;
    __syncthreads();
    int b0 = blockIdx.x * CHUNK;
    #pragma unroll
    for (int i = 0; i < CHUNK / 256; ++i) {
        int e = b0 + i * 256 + t;
        if (e < E) atomicAdd(&h[dst[e] >> BSHIFT], 1);
    }
    __syncthreads();
    if (h[t]) base[t] = atomicAdd(&bincnt[t * BPAD], h[t]);  // 1 line/bucket
    __syncthreads();
    #pragma unroll
    for (int i = 0; i < CHUNK / 256; ++i) {
        int e = b0 + i * 256 + t;
        if (e < E) {
            int d = dst[e];
            int b = d >> BSHIFT;
            int r = atomicAdd(&cnt[b], 1);
            binbuf[(size_t)b * CAP + base[b] + r] = (uint)(((d - (b << BSHIFT)) << 16) | src[e]);
        }
    }
}

// standalone GEMM (layer 2, dinv epilogue)
template <int CHAINS, bool SCALE>
__global__ __launch_bounds__(256) void k_gemm_mfma(const void* __restrict__ Xv,
                                                   const float* __restrict__ W,
                                                   const float* __restrict__ dinv,
                                                   ushort* __restrict__ Y, int M) {
    __shared__ alignas(16) ushort Xh[64][64];
    __shared__ alignas(16) ushort Xl[(CHAINS == 3) ? 64 : 1][64];
    __shared__ alignas(16) ushort Wth[128][64];
    __shared__ alignas(16) ushort Wtl[128][64];
    gemm_core<CHAINS, SCALE>(blockIdx.x, Xv, W, dinv, Y, M, Xh, Xl, Wth, Wtl);
}

// ---- per-bucket CSR: local deg -> scan -> row_ptr/deg/dinv + col scatter ----
__global__ __launch_bounds__(BNODES) void k_bucket(const uint* __restrict__ binbuf,
                                                   const int* __restrict__ bincnt,
                                                   int* __restrict__ row_ptr,
                                                   int* __restrict__ degO,
                                                   float* __restrict__ dinv,
                                                   int* __restrict__ col, int N) {
    __shared__ int sdeg[BNODES], sexcl[BNODES], scnt[BNODES];
    int b = blockIdx.x, t = threadIdx.x;
    int gnode = (b << BSHIFT) + t;
    sdeg[t] = 0;
    scnt[t] = 0;
    __syncthreads();
    int beg = b * CAP, count = bincnt[b * BPAD];
    for (int i = t; i < count; i += BNODES)
        atomicAdd(&sdeg[binbuf[beg + i] >> 16], 1);
    __syncthreads();
    int d = sdeg[t];
    sexcl[t] = d;
    __syncthreads();
    for (int off = 1; off < BNODES; off <<= 1) {
        int u = (t >= off) ? sexcl[t - off] : 0;
        __syncthreads();
        sexcl[t] += u;
        __syncthreads();
    }
    int excl = sexcl[t] - d;
    if (gnode < N) {
        row_ptr[gnode] = beg + excl;
        degO[gnode] = d;
        dinv[gnode] = rsqrtf((float)d + 1.0f);  // +1 self loop
    }
    __syncthreads();
    sexcl[t] = excl;
    __syncthreads();
    for (int i = t; i < count; i += BNODES) {
        uint p = binbuf[beg + i];
        int dl = p >> 16;
        int r = atomicAdd(&scnt[dl], 1);
        col[beg + sexcl[dl] + r] = (int)(p & 0xffffu);
    }
}

// ---- feature-partitioned aggregation ----
// block b: chunk=b>>3 (256 nodes), slot=b&7 -> group g=slot>>1 (32 features =
// 16 uints = one 64B line), half=slot&1 (128 nodes). Wave: 16 lanes x 4 edges;
// quarter q=lane>>4 handles edge e+q, lane&15 = uint within the group's line.
// SCALE_EDGES (layer1): y unscaled, acc += y[s]*dinv[s]; self*dn; out*dn+b,relu.
// FINAL: partial = sum_f relu(...)*Wf[f]; shfl-reduce; atomicAdd to out.
template <bool SCALE_EDGES, bool FINAL>
__global__ __launch_bounds__(256) void k_agg_feat(const uint* __restrict__ y,
                                                  const float* __restrict__ bvec,
                                                  const float* __restrict__ dinv,
                                                  const int* __restrict__ row_ptr,
                                                  const int* __restrict__ degA,
                                                  const int* __restrict__ col,
                                                  uint* __restrict__ h,
                                                  const float* __restrict__ Wf,
                                                  const float* __restrict__ bfp,
                                                  float* __restrict__ out, int N) {
    const int b = blockIdx.x;
    const int chunk = b >> 3, slot = b & 7;
    const int g = slot >> 1, half = slot & 1;
    const int t = threadIdx.x, wv = t >> 6, lane = t & 63;
    const int fi = (g << 4) + (lane & 15);   // uint index within row (0..63)
    const int q = lane >> 4;                 // edge sub-slot 0..3
    const int base = (chunk << 8) + (half << 7) + (wv << 5);

    for (int i = 0; i < 32; ++i) {
        int node = base + i;
        if (node >= N) return;
        int beg = row_ptr[node];
        int dg = degA[node];
        float dn = dinv[node];
        float2 acc = make_float2(0.f, 0.f);
        for (int ee = 0; ee < dg; ee += 4) {
            int idx = ee + q;
            bool v = idx < dg;
            int s = v ? col[beg + idx] : 0;
            uint u = v ? y[(size_t)s * 64 + fi] : 0u;
            float2 f = bf2f(u);
            if (SCALE_EDGES) {
                float ds = v ? dinv[s] : 0.f;
                acc.x = fmaf(f.x, ds, acc.x);
                acc.y = fmaf(f.y, ds, acc.y);
            } else {
                acc.x += f.x;
                acc.y += f.y;
            }
        }
        // reduce the 4 edge sub-slots (lanes l, l^16, l^32, l^48)
        acc.x += __shfl_xor(acc.x, 16); acc.y += __shfl_xor(acc.y, 16);
        acc.x += __shfl_xor(acc.x, 32); acc.y += __shfl_xor(acc.y, 32);
        // self loop
        float2 fs = bf2f(y[(size_t)node * 64 + fi]);
        if (SCALE_EDGES) {
            acc.x = fmaf(fs.x, dn, acc.x);
            acc.y = fmaf(fs.y, dn, acc.y);
        } else {
            acc.x += fs.x;
            acc.y += fs.y;
        }
        float2 bb = *(const float2*)&bvec[2 * fi];
        float ox = fmaxf(fmaf(acc.x, dn, bb.x), 0.f);
        float oy = fmaxf(fmaf(acc.y, dn, bb.y), 0.f);
        if (FINAL) {
            float2 wf = *(const float2*)&Wf[2 * fi];
            float p = ox * wf.x + oy * wf.y;
            p += __shfl_xor(p, 1);
            p += __shfl_xor(p, 2);
            p += __shfl_xor(p, 4);
            p += __shfl_xor(p, 8);
            if (lane == 0) atomicAdd(&out[node], p + (slot == 0 ? bfp[0] : 0.f));
        } else {
            if (lane < 16) h[(size_t)node * 64 + fi] = packbf2(ox, oy);
        }
    }
}

// ---------------- launch ----------------

extern "C" void kernel_launch(void* const* d_in, const int* in_sizes, int n_in,
                              void* d_out, int out_size, void* d_ws, size_t ws_size,
                              hipStream_t stream) {
    const float* x  = (const float*)d_in[0];
    const int*   ei = (const int*)d_in[1];
    const float* W1 = (const float*)d_in[2];
    const float* b1 = (const float*)d_in[3];
    const float* W2 = (const float*)d_in[4];
    const float* b2 = (const float*)d_in[5];
    const float* Wf = (const float*)d_in[6];
    const float* bf = (const float*)d_in[7];

    const int N = in_sizes[0] / FDIM;
    const int E = in_sizes[1] / 2;
    const int* src = ei;
    const int* dst = ei + E;
    const int nb = (N + BNODES - 1) >> BSHIFT;  // 196

    char* ws = (char*)d_ws;
    size_t off = 0;
    auto alloc = [&](size_t bytes) -> void* {
        void* p = ws + off;
        off = (off + bytes + 511) & ~(size_t)511;
        return p;
    };
    uint*  bufA    = (uint*)alloc((size_t)N * FDIM * 2);      // y1 (unscaled) / y2 (scaled)
    uint*  bufB    = (uint*)alloc((size_t)N * FDIM * 2);      // h1 bf16
    int*   col     = (int*)alloc((size_t)nb * CAP * 4);
    uint*  binbuf  = (uint*)alloc((size_t)nb * CAP * 4);
    float* dinv    = (float*)alloc((size_t)N * 4);
    int*   row_ptr = (int*)alloc((size_t)N * 4);
    int*   deg     = (int*)alloc((size_t)N * 4);
    int*   bincnt  = (int*)alloc(MAXB * BPAD * 4);

    hipMemsetAsync(bincnt, 0, MAXB * BPAD * 4, stream);
    hipMemsetAsync(d_out, 0, (size_t)out_size * 4, stream);  // FINAL accumulates

    const int nwg = (E + CHUNK - 1) / CHUNK;   // 391 scat blocks
    const int gb  = (N + 63) / 64;             // 782 gemm blocks
    const int ab  = ((N + 255) >> 8) * 8;      // 1568 agg blocks (chunk x 8 slots)

    // fused: bucket-scatter + layer-1 GEMM (unscaled y1 -> bufA)
    k_scat_gemm<<<nwg + gb, 256, 0, stream>>>(src, dst, bincnt, binbuf, E, nwg,
                                              x, W1, (ushort*)bufA, N);
    k_bucket<<<nb, BNODES, 0, stream>>>(binbuf, bincnt, row_ptr, deg, dinv, col, N);

    // layer-1 aggregation (feature-partitioned, per-edge dinv) -> h1
    k_agg_feat<true, false><<<ab, 256, 0, stream>>>(bufA, b1, dinv, row_ptr, deg, col,
                                                    bufB, nullptr, nullptr, nullptr, N);
    // layer-2 GEMM (dinv epilogue): h1 @ W2 -> y2 scaled -> bufA
    k_gemm_mfma<2, true><<<gb, 256, 0, stream>>>(bufB, W2, dinv, (ushort*)bufA, N);
    // final aggregation (feature-partitioned) + Wf dot -> out
    k_agg_feat<false, true><<<ab, 256, 0, stream>>>(bufA, b2, dinv, row_ptr, deg, col,
                                                    nullptr, Wf, bf, (float*)d_out, N);
}

// Round 14
// 201.781 us; speedup vs baseline: 2.0253x; 2.0253x over previous
//
#include <hip/hip_runtime.h>
#include <hip/hip_bf16.h>

// GCN anomaly detector: 2x GCNConv(128->128, relu) + linear(128->1).
// R14: revert to R11 structure (R12 agg+GEMM fusion and R13 feature-partition
// both destroyed gather TLP; XCD mapping assumption empirically false).
// Kept from R12: bincnt padded to one 64B line per counter (memory-side
// atomics to the same line serialize). Agg: one WAVE per node (TLP is the
// gather's lifeline), unroll 8 + mid 4 + scalar tail.
// Structure: fixed-capacity bucket CSR; GEMM1 fused into scatter launch;
// y1 UNSCALED (agg1 applies dinv[s] per edge); split-precision MFMA GEMMs.

#define FDIM 128
#define BSHIFT 8
#define BNODES 256
#define MAXB 256
#define BPAD 16     // bincnt stride in ints (64B line per counter)
#define CHUNK 2048
#define CAP 5120    // per-bucket capacity (mean 4096, sigma 64 -> 16 sigma)

typedef unsigned int uint;
typedef unsigned short ushort;
typedef __attribute__((ext_vector_type(8))) short short8v;
typedef __attribute__((ext_vector_type(4))) float f32x4;

__device__ inline float2 bf2f(uint u) {
    return make_float2(__uint_as_float(u << 16), __uint_as_float(u & 0xffff0000u));
}
__device__ inline ushort f2bf(float f) {
    uint u = __float_as_uint(f);
    return (ushort)((u + 0x7fffu + ((u >> 16) & 1u)) >> 16);  // RNE
}
__device__ inline float bfval(ushort h) { return __uint_as_float((uint)h << 16); }
__device__ inline uint packbf2(float a, float b) {
    return (uint)f2bf(a) | ((uint)f2bf(b) << 16);
}
// XOR-swizzle 16B granules within a row by row&7 (bank spread, b128-aligned).
__device__ inline int swz(int row, int colShorts) {
    return (((colShorts >> 3) ^ (row & 7)) << 3) | (colShorts & 7);
}

// ------- MFMA GEMM core (256 thr): Y[r,:] = bf16((X@W)[r,:]*(SCALE?dinv:1)) -------
template <int CHAINS, bool SCALE>
__device__ __forceinline__ void gemm_core(int bid, const void* __restrict__ Xv,
                                          const float* __restrict__ W,
                                          const float* __restrict__ dinv,
                                          ushort* __restrict__ Y, int M,
                                          ushort (*Xh)[64], ushort (*Xl)[64],
                                          ushort (*Wth)[64], ushort (*Wtl)[64]) {
    const int t = threadIdx.x;
    const int wv = t >> 6;
    const int lane = t & 63;
    const int rb = bid * 64;

    f32x4 acc[8];
    #pragma unroll
    for (int i = 0; i < 8; ++i) acc[i] = (f32x4){0.f, 0.f, 0.f, 0.f};

    for (int kc = 0; kc < 2; ++kc) {
        const int k0 = kc * 64;
        if constexpr (CHAINS == 3) {
            const float* Xf = (const float*)Xv;
            #pragma unroll
            for (int it = 0; it < 4; ++it) {
                int idx = t + it * 256;
                int r = idx >> 4, c4 = (idx & 15) * 4;
                int gr = rb + r;
                float4 v = make_float4(0.f, 0.f, 0.f, 0.f);
                if (gr < M) v = *(const float4*)&Xf[(size_t)gr * FDIM + k0 + c4];
                ushort h0 = f2bf(v.x), h1 = f2bf(v.y), h2 = f2bf(v.z), h3 = f2bf(v.w);
                uint2 hw, lw;
                hw.x = (uint)h0 | ((uint)h1 << 16);
                hw.y = (uint)h2 | ((uint)h3 << 16);
                lw.x = (uint)f2bf(v.x - bfval(h0)) | ((uint)f2bf(v.y - bfval(h1)) << 16);
                lw.y = (uint)f2bf(v.z - bfval(h2)) | ((uint)f2bf(v.w - bfval(h3)) << 16);
                int cs = swz(r, c4);
                *(uint2*)&Xh[r][cs] = hw;
                *(uint2*)&Xl[r][cs] = lw;
            }
        } else {
            const ushort* Xb = (const ushort*)Xv;
            #pragma unroll
            for (int it = 0; it < 4; ++it) {
                int idx = t + it * 256;
                int r = idx >> 4, c4 = (idx & 15) * 4;
                int gr = rb + r;
                uint2 u = make_uint2(0u, 0u);
                if (gr < M) u = *(const uint2*)&Xb[(size_t)gr * FDIM + k0 + c4];
                *(uint2*)&Xh[r][swz(r, c4)] = u;
            }
        }
        {   // stage W chunk transposed+split (64 k x 128 n), 256 threads
            int n = t & 127, kk0 = (t >> 7) * 32;
            #pragma unroll
            for (int g = 0; g < 4; ++g) {
                uint hw[4], lw[4];
                #pragma unroll
                for (int jp = 0; jp < 4; ++jp) {
                    int k = k0 + kk0 + g * 8 + jp * 2;
                    float w0 = W[(size_t)k * FDIM + n];
                    float w1 = W[(size_t)(k + 1) * FDIM + n];
                    ushort h0 = f2bf(w0), h1 = f2bf(w1);
                    hw[jp] = (uint)h0 | ((uint)h1 << 16);
                    lw[jp] = (uint)f2bf(w0 - bfval(h0)) | ((uint)f2bf(w1 - bfval(h1)) << 16);
                }
                int cs = swz(n, kk0 + g * 8);
                *(uint4*)&Wth[n][cs] = make_uint4(hw[0], hw[1], hw[2], hw[3]);
                *(uint4*)&Wtl[n][cs] = make_uint4(lw[0], lw[1], lw[2], lw[3]);
            }
        }
        __syncthreads();
        const int arow = 16 * wv + (lane & 15);
        #pragma unroll
        for (int ks = 0; ks < 2; ++ks) {
            const int kf = ks * 32 + ((lane >> 4) << 3);
            short8v ah = *(const short8v*)&Xh[arow][swz(arow, kf)];
            short8v al;
            if constexpr (CHAINS == 3) al = *(const short8v*)&Xl[arow][swz(arow, kf)];
            #pragma unroll
            for (int ct = 0; ct < 8; ++ct) {
                int brow = 16 * ct + (lane & 15);
                int bcs = swz(brow, kf);
                short8v bh = *(const short8v*)&Wth[brow][bcs];
                short8v bl = *(const short8v*)&Wtl[brow][bcs];
                acc[ct] = __builtin_amdgcn_mfma_f32_16x16x32_bf16(ah, bh, acc[ct], 0, 0, 0);
                acc[ct] = __builtin_amdgcn_mfma_f32_16x16x32_bf16(ah, bl, acc[ct], 0, 0, 0);
                if constexpr (CHAINS == 3)
                    acc[ct] = __builtin_amdgcn_mfma_f32_16x16x32_bf16(al, bh, acc[ct], 0, 0, 0);
            }
        }
        __syncthreads();
    }
    const int rbase = rb + 16 * wv + ((lane >> 4) << 2);
    const int cbase = lane & 15;
    #pragma unroll
    for (int ri = 0; ri < 4; ++ri) {
        int R = rbase + ri;
        if (R < M) {
            float s = SCALE ? dinv[R] : 1.0f;
            ushort* Yrow = Y + (size_t)R * FDIM;
            #pragma unroll
            for (int ct = 0; ct < 8; ++ct)
                Yrow[16 * ct + cbase] = f2bf(acc[ct][ri] * s);
        }
    }
}

// ---- fused: blocks [0,nwg) bucket-scatter; blocks [nwg,..) GEMM1 (unscaled) ----
__global__ __launch_bounds__(256) void k_scat_gemm(const int* __restrict__ src,
                                                   const int* __restrict__ dst,
                                                   int* __restrict__ bincnt,
                                                   uint* __restrict__ binbuf, int E, int nwg,
                                                   const void* __restrict__ Xv,
                                                   const float* __restrict__ W,
                                                   ushort* __restrict__ Y, int M) {
    __shared__ alignas(16) ushort Xh[64][64];
    __shared__ alignas(16) ushort Xl[64][64];
    __shared__ alignas(16) ushort Wth[128][64];
    __shared__ alignas(16) ushort Wtl[128][64];
    __shared__ int h[MAXB], base[MAXB], cnt[MAXB];

    if (blockIdx.x >= nwg) {
        gemm_core<3, false>(blockIdx.x - nwg, Xv, W, nullptr, Y, M, Xh, Xl, Wth, Wtl);
        return;
    }
    int t = threadIdx.x;
    h[t] = 0;
    cnt[t] = 0;
    __syncthreads();
    int b0 = blockIdx.x * CHUNK;
    #pragma unroll
    for (int i = 0; i < CHUNK / 256; ++i) {
        int e = b0 + i * 256 + t;
        if (e < E) atomicAdd(&h[dst[e] >> BSHIFT], 1);
    }
    __syncthreads();
    if (h[t]) base[t] = atomicAdd(&bincnt[t * BPAD], h[t]);  // 1 line/bucket: parallel
    __syncthreads();
    #pragma unroll
    for (int i = 0; i < CHUNK / 256; ++i) {
        int e = b0 + i * 256 + t;
        if (e < E) {
            int d = dst[e];
            int b = d >> BSHIFT;
            int r = atomicAdd(&cnt[b], 1);
            binbuf[(size_t)b * CAP + base[b] + r] = (uint)(((d - (b << BSHIFT)) << 16) | src[e]);
        }
    }
}

// standalone GEMM (layer 2, dinv epilogue)
template <int CHAINS, bool SCALE>
__global__ __launch_bounds__(256) void k_gemm_mfma(const void* __restrict__ Xv,
                                                   const float* __restrict__ W,
                                                   const float* __restrict__ dinv,
                                                   ushort* __restrict__ Y, int M) {
    __shared__ alignas(16) ushort Xh[64][64];
    __shared__ alignas(16) ushort Xl[(CHAINS == 3) ? 64 : 1][64];
    __shared__ alignas(16) ushort Wth[128][64];
    __shared__ alignas(16) ushort Wtl[128][64];
    gemm_core<CHAINS, SCALE>(blockIdx.x, Xv, W, dinv, Y, M, Xh, Xl, Wth, Wtl);
}

// ---- per-bucket CSR: local deg -> scan -> row_ptr/deg/dinv + col scatter ----
__global__ __launch_bounds__(BNODES) void k_bucket(const uint* __restrict__ binbuf,
                                                   const int* __restrict__ bincnt,
                                                   int* __restrict__ row_ptr,
                                                   int* __restrict__ degO,
                                                   float* __restrict__ dinv,
                                                   int* __restrict__ col, int N) {
    __shared__ int sdeg[BNODES], sexcl[BNODES], scnt[BNODES];
    int b = blockIdx.x, t = threadIdx.x;
    int gnode = (b << BSHIFT) + t;
    sdeg[t] = 0;
    scnt[t] = 0;
    __syncthreads();
    int beg = b * CAP, count = bincnt[b * BPAD];
    for (int i = t; i < count; i += BNODES)
        atomicAdd(&sdeg[binbuf[beg + i] >> 16], 1);
    __syncthreads();
    int d = sdeg[t];
    sexcl[t] = d;
    __syncthreads();
    for (int off = 1; off < BNODES; off <<= 1) {
        int u = (t >= off) ? sexcl[t - off] : 0;
        __syncthreads();
        sexcl[t] += u;
        __syncthreads();
    }
    int excl = sexcl[t] - d;
    if (gnode < N) {
        row_ptr[gnode] = beg + excl;
        degO[gnode] = d;
        dinv[gnode] = rsqrtf((float)d + 1.0f);  // +1 self loop
    }
    __syncthreads();
    sexcl[t] = excl;
    __syncthreads();
    for (int i = t; i < count; i += BNODES) {
        uint p = binbuf[beg + i];
        int dl = p >> 16;
        int r = atomicAdd(&scnt[dl], 1);
        col[beg + sexcl[dl] + r] = (int)(p & 0xffffu);
    }
}

// ------- Aggregation: one WAVE per node (TLP). SCALE_EDGES: y unscaled,
// apply dinv[s] per edge. FINAL fuses the Wf dot.
template <bool SCALE_EDGES, bool FINAL>
__global__ __launch_bounds__(256) void k_agg(const uint* __restrict__ y,
                                             const float* __restrict__ bvec,
                                             const float* __restrict__ dinv,
                                             const int* __restrict__ row_ptr,
                                             const int* __restrict__ degA,
                                             const int* __restrict__ col,
                                             uint* __restrict__ h,
                                             const float* __restrict__ Wf,
                                             const float* __restrict__ bfp,
                                             float* __restrict__ out, int n) {
    int wid = threadIdx.x >> 6, lane = threadIdx.x & 63;
    int node = blockIdx.x * 4 + wid;
    if (node >= n) return;
    int beg = row_ptr[node], end = beg + degA[node];
    float dn = dinv[node];
    float2 acc = bf2f(y[(size_t)node * 64 + lane]);  // self loop
    if (SCALE_EDGES) { acc.x *= dn; acc.y *= dn; }   // y unscaled: self norm = dn^2
    int e = beg;
    for (; e + 8 <= end; e += 8) {
        int s0 = col[e],     s1 = col[e + 1], s2 = col[e + 2], s3 = col[e + 3];
        int s4 = col[e + 4], s5 = col[e + 5], s6 = col[e + 6], s7 = col[e + 7];
        uint v0 = y[(size_t)s0 * 64 + lane];
        uint v1 = y[(size_t)s1 * 64 + lane];
        uint v2 = y[(size_t)s2 * 64 + lane];
        uint v3 = y[(size_t)s3 * 64 + lane];
        uint v4 = y[(size_t)s4 * 64 + lane];
        uint v5 = y[(size_t)s5 * 64 + lane];
        uint v6 = y[(size_t)s6 * 64 + lane];
        uint v7 = y[(size_t)s7 * 64 + lane];
        float2 f0 = bf2f(v0), f1 = bf2f(v1), f2 = bf2f(v2), f3 = bf2f(v3);
        float2 f4 = bf2f(v4), f5 = bf2f(v5), f6 = bf2f(v6), f7 = bf2f(v7);
        if (SCALE_EDGES) {
            float d0 = dinv[s0], d1 = dinv[s1], d2 = dinv[s2], d3 = dinv[s3];
            float d4 = dinv[s4], d5 = dinv[s5], d6 = dinv[s6], d7 = dinv[s7];
            acc.x = fmaf(f0.x, d0, acc.x); acc.y = fmaf(f0.y, d0, acc.y);
            acc.x = fmaf(f1.x, d1, acc.x); acc.y = fmaf(f1.y, d1, acc.y);
            acc.x = fmaf(f2.x, d2, acc.x); acc.y = fmaf(f2.y, d2, acc.y);
            acc.x = fmaf(f3.x, d3, acc.x); acc.y = fmaf(f3.y, d3, acc.y);
            acc.x = fmaf(f4.x, d4, acc.x); acc.y = fmaf(f4.y, d4, acc.y);
            acc.x = fmaf(f5.x, d5, acc.x); acc.y = fmaf(f5.y, d5, acc.y);
            acc.x = fmaf(f6.x, d6, acc.x); acc.y = fmaf(f6.y, d6, acc.y);
            acc.x = fmaf(f7.x, d7, acc.x); acc.y = fmaf(f7.y, d7, acc.y);
        } else {
            acc.x += ((f0.x + f1.x) + (f2.x + f3.x)) + ((f4.x + f5.x) + (f6.x + f7.x));
            acc.y += ((f0.y + f1.y) + (f2.y + f3.y)) + ((f4.y + f5.y) + (f6.y + f7.y));
        }
    }
    if (e + 4 <= end) {   // mid tail: 4 in flight
        int s0 = col[e], s1 = col[e + 1], s2 = col[e + 2], s3 = col[e + 3];
        uint v0 = y[(size_t)s0 * 64 + lane];
        uint v1 = y[(size_t)s1 * 64 + lane];
        uint v2 = y[(size_t)s2 * 64 + lane];
        uint v3 = y[(size_t)s3 * 64 + lane];
        float2 f0 = bf2f(v0), f1 = bf2f(v1), f2 = bf2f(v2), f3 = bf2f(v3);
        if (SCALE_EDGES) {
            float d0 = dinv[s0], d1 = dinv[s1], d2 = dinv[s2], d3 = dinv[s3];
            acc.x = fmaf(f0.x, d0, acc.x); acc.y = fmaf(f0.y, d0, acc.y);
            acc.x = fmaf(f1.x, d1, acc.x); acc.y = fmaf(f1.y, d1, acc.y);
            acc.x = fmaf(f2.x, d2, acc.x); acc.y = fmaf(f2.y, d2, acc.y);
            acc.x = fmaf(f3.x, d3, acc.x); acc.y = fmaf(f3.y, d3, acc.y);
        } else {
            acc.x += (f0.x + f1.x) + (f2.x + f3.x);
            acc.y += (f0.y + f1.y) + (f2.y + f3.y);
        }
        e += 4;
    }
    for (; e < end; ++e) {
        int s = col[e];
        float2 f = bf2f(y[(size_t)s * 64 + lane]);
        if (SCALE_EDGES) {
            float ds = dinv[s];
            acc.x = fmaf(f.x, ds, acc.x);
            acc.y = fmaf(f.y, ds, acc.y);
        } else {
            acc.x += f.x;
            acc.y += f.y;
        }
    }
    float2 bb = *(const float2*)&bvec[lane * 2];
    float ox = fmaxf(fmaf(acc.x, dn, bb.x), 0.f);
    float oy = fmaxf(fmaf(acc.y, dn, bb.y), 0.f);
    if (FINAL) {
        float2 wf = *(const float2*)&Wf[lane * 2];
        float s = ox * wf.x + oy * wf.y;
        #pragma unroll
        for (int off = 32; off > 0; off >>= 1) s += __shfl_xor(s, off);
        if (lane == 0) out[node] = s + bfp[0];
    } else {
        h[(size_t)node * 64 + lane] = packbf2(ox, oy);
    }
}

// ---------------- launch ----------------

extern "C" void kernel_launch(void* const* d_in, const int* in_sizes, int n_in,
                              void* d_out, int out_size, void* d_ws, size_t ws_size,
                              hipStream_t stream) {
    const float* x  = (const float*)d_in[0];
    const int*   ei = (const int*)d_in[1];
    const float* W1 = (const float*)d_in[2];
    const float* b1 = (const float*)d_in[3];
    const float* W2 = (const float*)d_in[4];
    const float* b2 = (const float*)d_in[5];
    const float* Wf = (const float*)d_in[6];
    const float* bf = (const float*)d_in[7];

    const int N = in_sizes[0] / FDIM;
    const int E = in_sizes[1] / 2;
    const int* src = ei;
    const int* dst = ei + E;
    const int nb = (N + BNODES - 1) >> BSHIFT;  // 196

    char* ws = (char*)d_ws;
    size_t off = 0;
    auto alloc = [&](size_t bytes) -> void* {
        void* p = ws + off;
        off = (off + bytes + 511) & ~(size_t)511;
        return p;
    };
    uint*  bufA    = (uint*)alloc((size_t)N * FDIM * 2);      // y1 (unscaled) / y2 (scaled)
    uint*  bufB    = (uint*)alloc((size_t)N * FDIM * 2);      // h1 bf16
    int*   col     = (int*)alloc((size_t)nb * CAP * 4);
    uint*  binbuf  = (uint*)alloc((size_t)nb * CAP * 4);
    float* dinv    = (float*)alloc((size_t)N * 4);
    int*   row_ptr = (int*)alloc((size_t)N * 4);
    int*   deg     = (int*)alloc((size_t)N * 4);
    int*   bincnt  = (int*)alloc(MAXB * BPAD * 4);

    hipMemsetAsync(bincnt, 0, MAXB * BPAD * 4, stream);

    const int nwg = (E + CHUNK - 1) / CHUNK;   // 391 scat blocks
    const int gb  = (N + 63) / 64;             // 782 gemm blocks
    // fused: bucket-scatter + layer-1 GEMM (unscaled y1 -> bufA)
    k_scat_gemm<<<nwg + gb, 256, 0, stream>>>(src, dst, bincnt, binbuf, E, nwg,
                                              x, W1, (ushort*)bufA, N);
    k_bucket<<<nb, BNODES, 0, stream>>>(binbuf, bincnt, row_ptr, deg, dinv, col, N);

    // layer-1 aggregation (per-edge dinv) -> h1
    k_agg<true, false><<<(N + 3) / 4, 256, 0, stream>>>(bufA, b1, dinv, row_ptr, deg, col,
                                                        bufB, nullptr, nullptr, nullptr, N);
    // layer-2 GEMM (dinv epilogue): h1 @ W2 -> y2 scaled -> bufA
    k_gemm_mfma<2, true><<<gb, 256, 0, stream>>>(bufB, W2, dinv, (ushort*)bufA, N);
    // final aggregation + Wf dot
    k_agg<false, true><<<(N + 3) / 4, 256, 0, stream>>>(bufA, b2, dinv, row_ptr, deg, col,
                                                        nullptr, Wf, bf, (float*)d_out, N);
}